// Round 7
// baseline (62.409 us; speedup 1.0000x reference)
//
#include <hip/hip_runtime.h>
#include <hip/hip_bf16.h>

#define NB 8
#define SEQ 2048
#define DIN 1024
#define DH 64

typedef __attribute__((ext_vector_type(8))) short bf16x8;
typedef __attribute__((ext_vector_type(4))) float f32x4;
typedef __attribute__((ext_vector_type(4))) unsigned int u32x4;

static __device__ __forceinline__ unsigned short f2bf(float f) {
    unsigned int u = __builtin_bit_cast(unsigned int, f);
    unsigned int r = (u + 0x7FFFu + ((u >> 16) & 1u)) >> 16;
    return (unsigned short)r;
}

static __device__ __forceinline__ unsigned int cvt_pk_bf16(float lo, float hi) {
    unsigned int d;
    asm volatile("v_cvt_pk_bf16_f32 %0, %1, %2" : "=v"(d) : "v"(lo), "v"(hi));
    return d;
}

// async global->LDS, 16B per lane, linear LDS dest (wave-uniform base + lane*16)
static __device__ __forceinline__ void gll16(const void* g, void* l) {
    __builtin_amdgcn_global_load_lds((const __attribute__((address_space(1))) unsigned int*)g,
                                     (__attribute__((address_space(3))) unsigned int*)l, 16, 0, 0);
}

#define WAITVM(N) asm volatile("s_waitcnt vmcnt(" #N ")" ::: "memory")

// ---------------- prep: pack W k-major fragment-linear:
// idx = (kk*12 + cg)*512 + cl*32 + kq*8 + ke ; col = cg*16+cl (mat=col>>6), k = kk*32+kq*8+ke
// so the 24KB tile for K-step t (kk = 2t, 2t+1) is CONTIGUOUS (linear global_load_lds copy).
__global__ __launch_bounds__(256) void prep_kernel(
    const float* __restrict__ Wq, const float* __restrict__ Wk, const float* __restrict__ Wv,
    unsigned short* __restrict__ Wfrag)
{
    int j = blockIdx.x * 256 + threadIdx.x;     // 0 .. 196607
    int mat = j >> 16;
    int rem = j & 65535;
    int k = rem >> 6;
    int c = rem & 63;
    const float* W = (mat == 0) ? Wq : ((mat == 1) ? Wk : Wv);
    float v = W[rem];
    int col = mat * 64 + c;
    int cg = col >> 4, cl = col & 15;
    int kk = k >> 5, kq = (k >> 3) & 3, ke = k & 7;
    Wfrag[(size_t)(kk * 12 + cg) * 512 + cl * 32 + kq * 8 + ke] = f2bf(v);
}

// ---------------- QKV GEMM: BM=32, BK=64, 512 blocks (2/CU).
// global_load_lds staging (X f32 source-swizzled, W linear), counted vmcnt,
// raw s_barrier (ONE per step) -> prefetches survive barriers.
__global__ __launch_bounds__(256) void qkv_kernel(
    const float* __restrict__ X, const unsigned short* __restrict__ Wfrag,
    const float* __restrict__ bq, const float* __restrict__ bk, const float* __restrict__ bv,
    unsigned short* __restrict__ Qb, unsigned short* __restrict__ Kb, unsigned short* __restrict__ Vt)
{
    __shared__ __align__(16) unsigned char Xs[3][8192];    // [32 rows][64 f32], src-swizzled
    __shared__ __align__(16) unsigned char Ws[2][24576];   // fragment-linear tile

    const int tid = threadIdx.x;
    const int w   = tid >> 6;
    const int l15 = tid & 15;
    const int lq  = (tid >> 4) & 3;
    const int row0 = blockIdx.x * 32;

    const char* Xg = (const char*)(X + (size_t)row0 * DIN);
    const char* Wg = (const char*)Wfrag;

    // X staging map: lds byte b -> row=b>>8, granule g=(b>>4)&15; source granule = g ^ (row&7)
    int xlds[2], xsrc[2];
    #pragma unroll
    for (int i = 0; i < 2; ++i) {
        int b = i * 4096 + tid * 16;
        int row = b >> 8;
        int g = (b >> 4) & 15;
        xlds[i] = b;
        xsrc[i] = row * 4096 + (g ^ (row & 7)) * 16;
    }

    f32x4 acc[2][3] = {};

    // prologue: X0, W0, X1
    #pragma unroll
    for (int i = 0; i < 2; ++i) gll16(Xg + (size_t)xsrc[i], &Xs[0][xlds[i]]);
    #pragma unroll
    for (int i = 0; i < 6; ++i) gll16(Wg + (size_t)(i * 4096 + tid * 16), &Ws[0][i * 4096 + tid * 16]);
    #pragma unroll
    for (int i = 0; i < 2; ++i) gll16(Xg + (size_t)xsrc[i] + 256, &Xs[1][xlds[i]]);

    #pragma unroll
    for (int t = 0; t < 16; ++t) {
        // wait for tile t (X(t+1) still in flight = 2 loads), sync waves
        if (t < 15) { WAITVM(2); } else { WAITVM(0); }
        __builtin_amdgcn_s_barrier();
        __builtin_amdgcn_sched_barrier(0);

        // issue next tiles immediately (buffers (t+1)&1 / (t+2)%3 are idle: all waves
        // passed the barrier above, so compute(t-1) reads are complete)
        if (t + 1 < 16) {
            #pragma unroll
            for (int i = 0; i < 6; ++i)
                gll16(Wg + (size_t)(t + 1) * 24576 + i * 4096 + tid * 16,
                      &Ws[(t + 1) & 1][i * 4096 + tid * 16]);
        }
        if (t + 2 < 16) {
            #pragma unroll
            for (int i = 0; i < 2; ++i)
                gll16(Xg + (size_t)xsrc[i] + (t + 2) * 256, &Xs[(t + 2) % 3][xlds[i]]);
        }

        const unsigned char* xb = Xs[t % 3];
        const unsigned char* wt = Ws[t & 1];
        #pragma unroll
        for (int kk = 0; kk < 2; ++kk) {
            bf16x8 a[2];
            #pragma unroll
            for (int m = 0; m < 2; ++m) {
                int row = m * 16 + l15;
                const unsigned char* rp = xb + row * 256;
                f32x4 f0 = *(const f32x4*)(rp + ((kk * 8 + lq * 2 + 0) ^ (row & 7)) * 16);
                f32x4 f1 = *(const f32x4*)(rp + ((kk * 8 + lq * 2 + 1) ^ (row & 7)) * 16);
                u32x4 pk;
                pk[0] = cvt_pk_bf16(f0[0], f0[1]);
                pk[1] = cvt_pk_bf16(f0[2], f0[3]);
                pk[2] = cvt_pk_bf16(f1[0], f1[1]);
                pk[3] = cvt_pk_bf16(f1[2], f1[3]);
                a[m] = __builtin_bit_cast(bf16x8, pk);
            }
            #pragma unroll
            for (int n = 0; n < 3; ++n) {
                bf16x8 bf = *(const bf16x8*)(wt + (kk * 12 + w * 3 + n) * 1024 + (l15 * 4 + lq) * 16);
                acc[0][n] = __builtin_amdgcn_mfma_f32_16x16x32_bf16(a[0], bf, acc[0][n], 0, 0, 0);
                acc[1][n] = __builtin_amdgcn_mfma_f32_16x16x32_bf16(a[1], bf, acc[1][n], 0, 0, 0);
            }
        }
    }

    // epilogue
    #pragma unroll
    for (int n = 0; n < 3; ++n) {
        int col = w * 48 + n * 16 + l15;
        int mat = col >> 6, c = col & 63;
        float badd = ((mat == 0) ? bq : ((mat == 1) ? bk : bv))[c];
        #pragma unroll
        for (int m = 0; m < 2; ++m) {
            #pragma unroll
            for (int reg = 0; reg < 4; ++reg) {
                int row = row0 + m * 16 + lq * 4 + reg;
                unsigned short v16 = f2bf(acc[m][n][reg] + badd);
                if (mat == 0)      Qb[(size_t)row * DH + c] = v16;
                else if (mat == 1) Kb[(size_t)row * DH + c] = v16;
                else {
                    int bb = row >> 11, ss = row & 2047;
                    Vt[((size_t)(bb * DH + c)) * SEQ + ss] = v16;
                }
            }
        }
    }
}

// ---------------- flash attention (fixed-max), 4-way key split, counted-vmcnt pipeline.
// block = (b, 64 q-rows, key-quarter of 512 keys); 256 thr / 4 waves; KT=64, triple-buffered.
#define AKT 64
#define ANT 8
#define PP 36

__global__ __launch_bounds__(256) void attn_kernel(
    const unsigned short* __restrict__ Qb, const unsigned short* __restrict__ Kb,
    const unsigned short* __restrict__ Vt, const int* __restrict__ mask,
    float* __restrict__ Opart, float* __restrict__ lpart)
{
    __shared__ __align__(16) unsigned char Ksm[3][8192];   // [64 keys][64 d] bf16, src-swizzled
    __shared__ __align__(16) unsigned char Vsm[3][8192];   // [64 d][64 keys] bf16, src-swizzled
    __shared__ short ps[4][32][PP];
    __shared__ float sml[4][32];

    const int tid = threadIdx.x;
    const int w   = tid >> 6;
    const int l15 = tid & 15;
    const int lq  = (tid >> 4) & 3;
    const int wm  = w >> 1;
    const int wn  = w & 1;

    int bid = blockIdx.x;
    int sbid = (bid & 7) * 128 + (bid >> 3);   // one batch per XCD
    const int b   = sbid >> 7;
    const int qt  = (sbid >> 2) & 31;
    const int kq  = sbid & 3;
    const int q0  = qt * 64;
    const int kb0 = kq * 512;

    // persistent Q fragments (plain loads, drained before the pipeline starts)
    bf16x8 aq[2][2];
    #pragma unroll
    for (int m = 0; m < 2; ++m)
        #pragma unroll
        for (int kk = 0; kk < 2; ++kk)
            aq[m][kk] = *(const bf16x8*)(Qb + ((size_t)(b * SEQ + q0 + wm * 32 + m * 16 + l15)) * DH + kk * 32 + lq * 8);

    // mask bits preloaded so the main loop has ZERO compiler-emitted VMEM
    int mk[ANT][2];
    #pragma unroll
    for (int t = 0; t < ANT; ++t) {
        mk[t][0] = mask[b * SEQ + kb0 + t * AKT + wn * 32 + l15];
        mk[t][1] = mask[b * SEQ + kb0 + t * AKT + wn * 32 + 16 + l15];
    }
    WAITVM(0);

    const char* Kg = (const char*)Kb + (size_t)(b * SEQ + kb0) * DH * 2;
    const char* Vg = (const char*)Vt + ((size_t)(b * DH) * SEQ + kb0) * 2;

    // staging map: 128B rows, 8 granules; source granule = g ^ (row&7)
    int slds[2], ksrc[2], vsrc[2];
    #pragma unroll
    for (int i = 0; i < 2; ++i) {
        int bb = i * 4096 + tid * 16;
        int row = bb >> 7;
        int g = (bb >> 4) & 7;
        int gs = g ^ (row & 7);
        slds[i] = bb;
        ksrc[i] = row * 128 + gs * 16;
        vsrc[i] = row * 4096 + gs * 16;
    }

    f32x4 o[2][4];
    #pragma unroll
    for (int m = 0; m < 2; ++m)
        #pragma unroll
        for (int n = 0; n < 4; ++n) o[m][n] = f32x4{0, 0, 0, 0};
    float lr[2][4] = {};
    const float rscale = 0.022097086912079612f;  // 1/sqrt(2048)

    // prologue: tiles 0,1
    #pragma unroll
    for (int i = 0; i < 2; ++i) gll16(Kg + (size_t)ksrc[i], &Ksm[0][slds[i]]);
    #pragma unroll
    for (int i = 0; i < 2; ++i) gll16(Vg + (size_t)vsrc[i], &Vsm[0][slds[i]]);
    #pragma unroll
    for (int i = 0; i < 2; ++i) gll16(Kg + (size_t)8192 + ksrc[i], &Ksm[1][slds[i]]);
    #pragma unroll
    for (int i = 0; i < 2; ++i) gll16(Vg + (size_t)128 + vsrc[i], &Vsm[1][slds[i]]);

    #pragma unroll
    for (int t = 0; t < ANT; ++t) {
        if (t < ANT - 1) { WAITVM(4); } else { WAITVM(0); }
        __builtin_amdgcn_s_barrier();
        __builtin_amdgcn_sched_barrier(0);

        if (t + 2 < ANT) {
            int bi = (t + 2) % 3;
            #pragma unroll
            for (int i = 0; i < 2; ++i) gll16(Kg + (size_t)(t + 2) * 8192 + ksrc[i], &Ksm[bi][slds[i]]);
            #pragma unroll
            for (int i = 0; i < 2; ++i) gll16(Vg + (size_t)(t + 2) * 128 + vsrc[i], &Vsm[bi][slds[i]]);
        }

        const unsigned char* kt  = Ksm[t % 3];
        const unsigned char* vt2 = Vsm[t % 3];

        // ---- QK^T: 32 q-rows x 32 keys (this wave's wn-half)
        bf16x8 bkf[2][2];
        #pragma unroll
        for (int n = 0; n < 2; ++n)
            #pragma unroll
            for (int kk = 0; kk < 2; ++kk) {
                int row = wn * 32 + n * 16 + l15;
                bkf[n][kk] = *(const bf16x8*)(kt + row * 128 + ((4 * kk + lq) ^ (row & 7)) * 16);
            }
        f32x4 s[2][2];
        #pragma unroll
        for (int m = 0; m < 2; ++m)
            #pragma unroll
            for (int n = 0; n < 2; ++n) s[m][n] = f32x4{0, 0, 0, 0};
        #pragma unroll
        for (int kk = 0; kk < 2; ++kk)
            #pragma unroll
            for (int m = 0; m < 2; ++m)
                #pragma unroll
                for (int n = 0; n < 2; ++n)
                    s[m][n] = __builtin_amdgcn_mfma_f32_16x16x32_bf16(aq[m][kk], bkf[n][kk], s[m][n], 0, 0, 0);

        // ---- p = exp(s*scale + maskbias); per-lane partial l; P -> ps
        float bb0 = mk[t][0] ? -1e30f : 0.0f;
        float bb1 = mk[t][1] ? -1e30f : 0.0f;
        #pragma unroll
        for (int m = 0; m < 2; ++m)
            #pragma unroll
            for (int n = 0; n < 2; ++n) {
                float bvv = n ? bb1 : bb0;
                #pragma unroll
                for (int r = 0; r < 4; ++r) {
                    float p = __expf(fmaf(s[m][n][r], rscale, bvv));
                    lr[m][r] += p;
                    ps[w][m * 16 + lq * 4 + r][n * 16 + l15] = (short)f2bf(p);
                }
            }

        // ---- PV: P(32 x 32keys) x V(32keys x 64d)
        bf16x8 pa[2];
        #pragma unroll
        for (int m = 0; m < 2; ++m)
            pa[m] = *(const bf16x8*)&ps[w][m * 16 + l15][lq * 8];
        bf16x8 bvf[4];
        #pragma unroll
        for (int n = 0; n < 4; ++n) {
            int row = n * 16 + l15;
            bvf[n] = *(const bf16x8*)(vt2 + row * 128 + ((4 * wn + lq) ^ (row & 7)) * 16);
        }
        #pragma unroll
        for (int m = 0; m < 2; ++m)
            #pragma unroll
            for (int n = 0; n < 4; ++n)
                o[m][n] = __builtin_amdgcn_mfma_f32_16x16x32_bf16(pa[m], bvf[n], o[m][n], 0, 0, 0);
    }

    // ---- l partials: reduce over the 16 key-lanes
    #pragma unroll
    for (int off = 1; off < 16; off <<= 1)
        #pragma unroll
        for (int m = 0; m < 2; ++m)
            #pragma unroll
            for (int r = 0; r < 4; ++r) lr[m][r] += __shfl_xor(lr[m][r], off);
    if (l15 == 0) {
        #pragma unroll
        for (int m = 0; m < 2; ++m)
            #pragma unroll
            for (int r = 0; r < 4; ++r) sml[w][m * 16 + lq * 4 + r] = lr[m][r];
    }
    __syncthreads();   // all K/V reads done; overlay merge buffer on Ksm

    float (*mg)[32][64] = reinterpret_cast<float (*)[32][64]>(&Ksm[0][0]);  // 16 KiB
    if (wn == 1) {
        #pragma unroll
        for (int m = 0; m < 2; ++m)
            #pragma unroll
            for (int n = 0; n < 4; ++n)
                #pragma unroll
                for (int r = 0; r < 4; ++r)
                    mg[wm][m * 16 + lq * 4 + r][n * 16 + l15] = o[m][n][r];
    }
    __syncthreads();
    if (wn == 0) {
        #pragma unroll
        for (int m = 0; m < 2; ++m)
            #pragma unroll
            for (int n = 0; n < 4; ++n)
                #pragma unroll
                for (int r = 0; r < 4; ++r)
                    mg[wm][m * 16 + lq * 4 + r][n * 16 + l15] += o[m][n][r];
    }
    __syncthreads();

    // ---- write partial O (coalesced) and partial l
    {
        int qq = tid >> 2;            // 0..63
        int d0 = (tid & 3) * 16;      // 0,16,32,48
        float* dst = Opart + ((size_t)kq * (NB * SEQ) + b * SEQ + q0 + qq) * DH + d0;
        #pragma unroll
        for (int j = 0; j < 4; ++j)
            *(float4*)(dst + j * 4) = *(float4*)&mg[qq >> 5][qq & 31][d0 + j * 4];
    }
    if (tid < 64) {
        int wmi = tid >> 5;
        float lsum = sml[wmi * 2][tid & 31] + sml[wmi * 2 + 1][tid & 31];
        lpart[(size_t)kq * (NB * SEQ) + b * SEQ + q0 + tid] = lsum;
    }
}

// ---------------- merge: out = (sum_p Opart[p]) / (sum_p lpart[p])
__global__ __launch_bounds__(256) void merge_kernel(
    const float* __restrict__ Opart, const float* __restrict__ lpart,
    float* __restrict__ out)
{
    int bid = blockIdx.x;
    int sbid = (bid & 7) * 32 + (bid >> 3);   // match batch->XCD mapping
    int g = sbid * 256 + threadIdx.x;
    int q  = g >> 2;              // 0..16383
    int d0 = (g & 3) * 16;

    float l = lpart[q] + lpart[16384 + q] + lpart[2 * 16384 + q] + lpart[3 * 16384 + q];
    float inv = 1.0f / l;

    const float* o0 = Opart + (size_t)q * DH + d0;
    #pragma unroll
    for (int j = 0; j < 4; ++j) {
        float4 a = *(const float4*)(o0 + j * 4);
        float4 b2 = *(const float4*)(o0 + (size_t)16384 * DH + j * 4);
        float4 c = *(const float4*)(o0 + (size_t)2 * 16384 * DH + j * 4);
        float4 d = *(const float4*)(o0 + (size_t)3 * 16384 * DH + j * 4);
        float4 r;
        r.x = (a.x + b2.x + c.x + d.x) * inv;
        r.y = (a.y + b2.y + c.y + d.y) * inv;
        r.z = (a.z + b2.z + c.z + d.z) * inv;
        r.w = (a.w + b2.w + c.w + d.w) * inv;
        *(float4*)(out + (size_t)q * DH + d0 + j * 4) = r;
    }
}

extern "C" void kernel_launch(void* const* d_in, const int* in_sizes, int n_in,
                              void* d_out, int out_size, void* d_ws, size_t ws_size,
                              hipStream_t stream) {
    const float* X    = (const float*)d_in[0];
    const int*   mask = (const int*)d_in[1];
    const float* Wq   = (const float*)d_in[2];
    const float* bq   = (const float*)d_in[3];
    const float* Wk   = (const float*)d_in[4];
    const float* bk   = (const float*)d_in[5];
    const float* Wv   = (const float*)d_in[6];
    const float* bv   = (const float*)d_in[7];
    float* out = (float*)d_out;

    char* ws = (char*)d_ws;
    unsigned short* Qb    = (unsigned short*)(ws);                 // 2 MiB
    unsigned short* Kb    = (unsigned short*)(ws + (2u << 20));    // 2 MiB
    unsigned short* Vt    = (unsigned short*)(ws + (4u << 20));    // 2 MiB
    unsigned short* Wfrag = (unsigned short*)(ws + (6u << 20));    // 384 KiB
    float* Opart          = (float*)(ws + (8u << 20));             // 16 MiB
    float* lpart          = (float*)(ws + (24u << 20));            // 256 KiB

    prep_kernel<<<768, 256, 0, stream>>>(Wq, Wk, Wv, Wfrag);
    qkv_kernel<<<512, 256, 0, stream>>>(X, Wfrag, bq, bk, bv, Qb, Kb, Vt);
    attn_kernel<<<1024, 256, 0, stream>>>(Qb, Kb, Vt, mask, Opart, lpart);
    merge_kernel<<<256, 256, 0, stream>>>(Opart, lpart, out);
}